// Round 2
// baseline (1174.666 us; speedup 1.0000x reference)
//
#include <hip/hip_runtime.h>

// ---------------------------------------------------------------------------
// InterpretableMultiHeadAttention  (B=4, T=2048, D=512, H=8, dk=64)
// out0: [B,T,512] f32   out1(attn): [B,H,T,T] f32  (concatenated in d_out)
//
// Pipeline:
//  1) proj_gemm<0>: Q = query@Wq.T+bq  -> bf16 hi/lo, layout [B,H,T,64]
//     proj_gemm<0>: K = key @Wk.T+bk  -> bf16 hi/lo, layout [B,H,T,64]
//     proj_gemm<1>: V = value@Wv.T+bv -> bf16 hi/lo, layout Vt[b][n][t] (transposed)
//  2) attn_kernel: per (b,h,qtile64): 2-pass online softmax, writes attn f32
//  3) avgpv_kernel: per (b,qtile32): pavg = mean_h attn, tmp = pavg@V (split MFMA)
//  4) proj_gemm<2>: out0 = tmp@Wo.T+bo (f32)
//
// All matmuls use split-bf16 (hi + lo) 3-term MFMA => ~fp32 accuracy.
// ---------------------------------------------------------------------------

typedef __attribute__((ext_vector_type(4))) float fx4;
typedef __attribute__((ext_vector_type(8))) short s16x8;
typedef __attribute__((ext_vector_type(4))) short s16x4;

#define MFMA16(a, b, c) __builtin_amdgcn_mfma_f32_16x16x32_bf16((a), (b), (c), 0, 0, 0)

__device__ __forceinline__ unsigned short f2bf(float f) {
  unsigned int u = __builtin_bit_cast(unsigned int, f);
  u += 0x7FFFu + ((u >> 16) & 1u);
  return (unsigned short)(u >> 16);
}
__device__ __forceinline__ float bf2f(unsigned short h) {
  unsigned int u = ((unsigned int)h) << 16;
  return __builtin_bit_cast(float, u);
}
__device__ __forceinline__ void splitf(float x, unsigned short& h, unsigned short& l) {
  h = f2bf(x);
  float r = x - bf2f(h);
  l = f2bf(r);
}

// ---------------------------------------------------------------------------
// Generic projection GEMM: C[M=8192, N=512] = X[M,512] @ W[N,512]^T + bias[N]
// MODE 0: write bf16 hi/lo to [B,H,T,64] (Q/K)
// MODE 1: write bf16 hi/lo transposed Vt[b][n][t]
// MODE 2: write f32 [M,N] (final out)
// Tile 128x64, BK=32, 4 waves (2x2), per-wave 64x32 (4x2 16x16 frags).
// ---------------------------------------------------------------------------
template <int MODE>
__global__ __launch_bounds__(256) void proj_gemm(
    const float* __restrict__ X, const float* __restrict__ W,
    const float* __restrict__ bias, unsigned short* __restrict__ outH,
    unsigned short* __restrict__ outL, float* __restrict__ outF) {
  // row pitch 40 shorts = 80B = 5*16B: 16B-aligned frag reads, 2-way-max banks
  __shared__ __align__(16) short Ah[128][40];
  __shared__ __align__(16) short Al[128][40];
  __shared__ __align__(16) short Bh[64][40];
  __shared__ __align__(16) short Bl[64][40];

  const int tid = threadIdx.x;
  const int lane = tid & 63;
  const int wid = tid >> 6;
  const int wm = wid >> 1, wn = wid & 1;
  const int fr = lane & 15, fq = lane >> 4;
  const int m0 = blockIdx.x * 128;
  const int n0 = blockIdx.y * 64;

  fx4 acc[4][2];
#pragma unroll
  for (int i = 0; i < 4; ++i)
#pragma unroll
    for (int j = 0; j < 2; ++j) acc[i][j] = (fx4){0.f, 0.f, 0.f, 0.f};

  for (int k0 = 0; k0 < 512; k0 += 32) {
    __syncthreads();
    // stage A tile 128x32 f32 -> hi/lo bf16
#pragma unroll
    for (int i = 0; i < 4; ++i) {
      int fi = tid + i * 256;
      int row = fi >> 3, c4 = (fi & 7) * 4;
      fx4 v = *(const fx4*)&X[(size_t)(m0 + row) * 512 + k0 + c4];
      s16x4 h, l;
#pragma unroll
      for (int j = 0; j < 4; ++j) {
        unsigned short hh, ll;
        splitf(v[j], hh, ll);
        h[j] = (short)hh;
        l[j] = (short)ll;
      }
      *(s16x4*)&Ah[row][c4] = h;
      *(s16x4*)&Al[row][c4] = l;
    }
    // stage B tile 64x32 (rows of W)
#pragma unroll
    for (int i = 0; i < 2; ++i) {
      int fi = tid + i * 256;
      int row = fi >> 3, c4 = (fi & 7) * 4;
      fx4 v = *(const fx4*)&W[(size_t)(n0 + row) * 512 + k0 + c4];
      s16x4 h, l;
#pragma unroll
      for (int j = 0; j < 4; ++j) {
        unsigned short hh, ll;
        splitf(v[j], hh, ll);
        h[j] = (short)hh;
        l[j] = (short)ll;
      }
      *(s16x4*)&Bh[row][c4] = h;
      *(s16x4*)&Bl[row][c4] = l;
    }
    __syncthreads();

    s16x8 bh[2], bl[2];
#pragma unroll
    for (int ni = 0; ni < 2; ++ni) {
      bh[ni] = *(const s16x8*)&Bh[wn * 32 + ni * 16 + fr][fq * 8];
      bl[ni] = *(const s16x8*)&Bl[wn * 32 + ni * 16 + fr][fq * 8];
    }
#pragma unroll
    for (int mi = 0; mi < 4; ++mi) {
      s16x8 ah = *(const s16x8*)&Ah[wm * 64 + mi * 16 + fr][fq * 8];
      s16x8 al = *(const s16x8*)&Al[wm * 64 + mi * 16 + fr][fq * 8];
#pragma unroll
      for (int ni = 0; ni < 2; ++ni) {
        acc[mi][ni] = MFMA16(ah, bh[ni], acc[mi][ni]);
        acc[mi][ni] = MFMA16(ah, bl[ni], acc[mi][ni]);
        acc[mi][ni] = MFMA16(al, bh[ni], acc[mi][ni]);
      }
    }
  }

  // epilogue
#pragma unroll
  for (int mi = 0; mi < 4; ++mi) {
#pragma unroll
    for (int ni = 0; ni < 2; ++ni) {
      const int n = n0 + wn * 32 + ni * 16 + fr;
      const float bv = bias[n];
      const int mb = m0 + wm * 64 + mi * 16 + fq * 4;
      if (MODE == 0) {
#pragma unroll
        for (int r = 0; r < 4; ++r) {
          int m = mb + r;
          int b = m >> 11, t = m & 2047;
          int h = n >> 6, d = n & 63;
          size_t idx = (((size_t)(b * 8 + h) * 2048) + t) * 64 + d;
          unsigned short hh, ll;
          splitf(acc[mi][ni][r] + bv, hh, ll);
          outH[idx] = hh;
          outL[idx] = ll;
        }
      } else if (MODE == 1) {
        int b = mb >> 11, t = mb & 2047;  // 4 consecutive t, same n
        size_t idx = ((size_t)(b * 512 + n)) * 2048 + t;
        s16x4 hv, lv;
#pragma unroll
        for (int r = 0; r < 4; ++r) {
          unsigned short hh, ll;
          splitf(acc[mi][ni][r] + bv, hh, ll);
          hv[r] = (short)hh;
          lv[r] = (short)ll;
        }
        *(s16x4*)&outH[idx] = hv;
        *(s16x4*)&outL[idx] = lv;
      } else {
#pragma unroll
        for (int r = 0; r < 4; ++r) {
          outF[(size_t)(mb + r) * 512 + n] = acc[mi][ni][r] + bv;
        }
      }
    }
  }
}

// ---------------------------------------------------------------------------
// Attention: per block (b, h, qtile of 64). 4 waves, each 16 q rows.
// Two passes over 32 K-tiles of 64: pass0 = online max/sum, pass1 = write p.
// ---------------------------------------------------------------------------
__global__ __launch_bounds__(256) void attn_kernel(
    const unsigned short* __restrict__ Qh, const unsigned short* __restrict__ Ql,
    const unsigned short* __restrict__ Kh, const unsigned short* __restrict__ Kl,
    float* __restrict__ attn_out) {
  __shared__ __align__(16) short KhS[64][72];  // 144B pitch: aligned + low conflict
  __shared__ __align__(16) short KlS[64][72];

  const int tid = threadIdx.x;
  const int lane = tid & 63;
  const int wid = tid >> 6;
  const int bid = blockIdx.x;
  const int qt = bid & 31;
  const int h = (bid >> 5) & 7;
  const int b = bid >> 8;
  const int fr = lane & 15, fq = lane >> 4;
  const int q0 = qt * 64 + wid * 16;
  const size_t qkbase = ((size_t)(b * 8 + h)) * 2048;

  // Q fragments for this wave's 16 rows (kept in regs across both passes)
  s16x8 qfh[2], qfl[2];
#pragma unroll
  for (int kk = 0; kk < 2; ++kk) {
    size_t idx = (qkbase + q0 + fr) * 64 + kk * 32 + fq * 8;
    qfh[kk] = *(const s16x8*)&Qh[idx];
    qfl[kk] = *(const s16x8*)&Ql[idx];
  }

  float mrow[4], lrow[4];
#pragma unroll
  for (int r = 0; r < 4; ++r) {
    mrow[r] = -1e30f;
    lrow[r] = 0.f;
  }

  for (int pass = 0; pass < 2; ++pass) {
    for (int kt = 0; kt < 32; ++kt) {
      __syncthreads();
      // stage K tile 64x64 hi/lo (already bf16 in global)
#pragma unroll
      for (int i = 0; i < 2; ++i) {
        int fi = tid + i * 256;  // s16x8 units: 64 rows * 8 = 512
        int row = fi >> 3, c8 = (fi & 7) * 8;
        size_t g = (qkbase + kt * 64 + row) * 64 + c8;
        *(s16x8*)&KhS[row][c8] = *(const s16x8*)&Kh[g];
        *(s16x8*)&KlS[row][c8] = *(const s16x8*)&Kl[g];
      }
      __syncthreads();

      fx4 sf[4];
#pragma unroll
      for (int f = 0; f < 4; ++f) sf[f] = (fx4){0.f, 0.f, 0.f, 0.f};
#pragma unroll
      for (int f = 0; f < 4; ++f) {
#pragma unroll
        for (int kk = 0; kk < 2; ++kk) {
          s16x8 kh = *(const s16x8*)&KhS[f * 16 + fr][kk * 32 + fq * 8];
          s16x8 kl = *(const s16x8*)&KlS[f * 16 + fr][kk * 32 + fq * 8];
          sf[f] = MFMA16(qfh[kk], kh, sf[f]);
          sf[f] = MFMA16(qfh[kk], kl, sf[f]);
          sf[f] = MFMA16(qfl[kk], kh, sf[f]);
        }
      }

      if (pass == 0) {
#pragma unroll
        for (int r = 0; r < 4; ++r) {
          float tm = sf[0][r] * 0.125f;
#pragma unroll
          for (int f = 1; f < 4; ++f) tm = fmaxf(tm, sf[f][r] * 0.125f);
          tm = fmaxf(tm, __shfl_xor(tm, 1));
          tm = fmaxf(tm, __shfl_xor(tm, 2));
          tm = fmaxf(tm, __shfl_xor(tm, 4));
          tm = fmaxf(tm, __shfl_xor(tm, 8));
          float mn = fmaxf(mrow[r], tm);
          float ts = 0.f;
#pragma unroll
          for (int f = 0; f < 4; ++f) ts += __expf(sf[f][r] * 0.125f - mn);
          ts += __shfl_xor(ts, 1);
          ts += __shfl_xor(ts, 2);
          ts += __shfl_xor(ts, 4);
          ts += __shfl_xor(ts, 8);
          lrow[r] = lrow[r] * __expf(mrow[r] - mn) + ts;
          mrow[r] = mn;
        }
      } else {
#pragma unroll
        for (int r = 0; r < 4; ++r) {
          float inv = 1.f / lrow[r];
          size_t rowaddr = (qkbase + q0 + fq * 4 + r) * 2048 + kt * 64;
#pragma unroll
          for (int f = 0; f < 4; ++f) {
            float p = __expf(sf[f][r] * 0.125f - mrow[r]) * inv;
            attn_out[rowaddr + f * 16 + fr] = p;
          }
        }
      }
    }
  }
}

// ---------------------------------------------------------------------------
// avg + PV: per block (b, qtile of 32). 8 waves, each owns 64 output cols.
// tmp[b,q,0:512] = (mean_h attn[b,h,q,:]) @ V   (V from Vt hi/lo, split MFMA)
// ---------------------------------------------------------------------------
__global__ __launch_bounds__(512) void avgpv_kernel(
    const float* __restrict__ attn, const unsigned short* __restrict__ Vth,
    const unsigned short* __restrict__ Vtl, float* __restrict__ tmp) {
  __shared__ __align__(16) short Ph[32][72];
  __shared__ __align__(16) short Pl[32][72];

  const int tid = threadIdx.x;
  const int lane = tid & 63;
  const int wid = tid >> 6;  // 0..7
  const int bid = blockIdx.x;
  const int qt = bid & 63;  // 64 qtiles of 32 per batch
  const int b = bid >> 6;
  const int q0 = qt * 32;
  const int fr = lane & 15, fq = lane >> 4;

  fx4 acc[2][4];
#pragma unroll
  for (int i = 0; i < 2; ++i)
#pragma unroll
    for (int j = 0; j < 4; ++j) acc[i][j] = (fx4){0.f, 0.f, 0.f, 0.f};

  const int sq = tid >> 4;        // 0..31 (q row)
  const int sg = (tid & 15) * 4;  // kv col base
  const size_t arow = ((size_t)(b * 8) * 2048 + q0 + sq) * 2048 + sg;

  for (int kt = 0; kt < 32; ++kt) {
    __syncthreads();
    // stage pavg tile 32x64: read 8 heads, average, split to bf16 hi/lo
    fx4 ps = (fx4){0.f, 0.f, 0.f, 0.f};
#pragma unroll
    for (int hh = 0; hh < 8; ++hh) {
      fx4 v = *(const fx4*)&attn[arow + (size_t)hh * 4194304 + kt * 64];
      ps += v;
    }
    ps *= 0.125f;
    s16x4 ph, pl;
#pragma unroll
    for (int j = 0; j < 4; ++j) {
      unsigned short hh, ll;
      splitf(ps[j], hh, ll);
      ph[j] = (short)hh;
      pl[j] = (short)ll;
    }
    *(s16x4*)&Ph[sq][sg] = ph;
    *(s16x4*)&Pl[sq][sg] = pl;
    __syncthreads();

#pragma unroll
    for (int kk = 0; kk < 2; ++kk) {
      s16x8 ah[2], al[2];
#pragma unroll
      for (int mi = 0; mi < 2; ++mi) {
        ah[mi] = *(const s16x8*)&Ph[mi * 16 + fr][kk * 32 + fq * 8];
        al[mi] = *(const s16x8*)&Pl[mi * 16 + fr][kk * 32 + fq * 8];
      }
#pragma unroll
      for (int ni = 0; ni < 4; ++ni) {
        int n = wid * 64 + ni * 16 + fr;
        size_t vb = ((size_t)(b * 512 + n)) * 2048 + kt * 64 + kk * 32 + fq * 8;
        s16x8 vh = *(const s16x8*)&Vth[vb];
        s16x8 vl = *(const s16x8*)&Vtl[vb];
#pragma unroll
        for (int mi = 0; mi < 2; ++mi) {
          acc[mi][ni] = MFMA16(ah[mi], vh, acc[mi][ni]);
          acc[mi][ni] = MFMA16(ah[mi], vl, acc[mi][ni]);
          acc[mi][ni] = MFMA16(al[mi], vh, acc[mi][ni]);
        }
      }
    }
  }

#pragma unroll
  for (int mi = 0; mi < 2; ++mi)
#pragma unroll
    for (int ni = 0; ni < 4; ++ni)
#pragma unroll
      for (int r = 0; r < 4; ++r) {
        int row = q0 + mi * 16 + fq * 4 + r;
        int n = wid * 64 + ni * 16 + fr;
        tmp[((size_t)(b * 2048 + row)) * 512 + n] = acc[mi][ni][r];
      }
}

// ---------------------------------------------------------------------------
extern "C" void kernel_launch(void* const* d_in, const int* in_sizes, int n_in,
                              void* d_out, int out_size, void* d_ws,
                              size_t ws_size, hipStream_t stream) {
  const float* query = (const float*)d_in[0];
  const float* key_in = (const float*)d_in[1];
  const float* value = (const float*)d_in[2];
  const float* Wq = (const float*)d_in[3];
  const float* bq = (const float*)d_in[4];
  const float* Wk = (const float*)d_in[5];
  const float* bk = (const float*)d_in[6];
  const float* Wv = (const float*)d_in[7];
  const float* bv = (const float*)d_in[8];
  const float* Wo = (const float*)d_in[9];
  const float* bo = (const float*)d_in[10];

  float* out0 = (float*)d_out;                    // [B,T,512]
  float* attn = out0 + (size_t)4 * 2048 * 512;    // [B,H,T,T]

  char* ws = (char*)d_ws;
  const size_t SZ = (size_t)8192 * 512 * 2;  // one bf16 plane: 8.39MB
  unsigned short* Qh = (unsigned short*)(ws + 0 * SZ);
  unsigned short* Ql = (unsigned short*)(ws + 1 * SZ);
  unsigned short* Kh = (unsigned short*)(ws + 2 * SZ);
  unsigned short* Kl = (unsigned short*)(ws + 3 * SZ);
  unsigned short* Vth = (unsigned short*)(ws + 4 * SZ);
  unsigned short* Vtl = (unsigned short*)(ws + 5 * SZ);
  float* tmp = (float*)(ws + 6 * SZ);  // 16.78MB; total ws use = 67.1MB

  dim3 pgrid(64, 8);
  proj_gemm<0><<<pgrid, 256, 0, stream>>>(query, Wq, bq, Qh, Ql, nullptr);
  proj_gemm<0><<<pgrid, 256, 0, stream>>>(key_in, Wk, bk, Kh, Kl, nullptr);
  proj_gemm<1><<<pgrid, 256, 0, stream>>>(value, Wv, bv, Vth, Vtl, nullptr);
  attn_kernel<<<1024, 256, 0, stream>>>(Qh, Ql, Kh, Kl, attn);
  avgpv_kernel<<<256, 512, 0, stream>>>(attn, Vth, Vtl, tmp);
  proj_gemm<2><<<pgrid, 256, 0, stream>>>(tmp, Wo, bo, nullptr, nullptr, out0);
}